// Round 1
// baseline (960.454 us; speedup 1.0000x reference)
//
#include <hip/hip_runtime.h>
#include <math.h>

#define H 1024
#define H4 256          // H/4
#define ML 4096
#define V 128000

// ---------------- K1: attn_logits[m] = dot(concat(e0,h0), attn_w[m]) + attn_b[m]
__global__ __launch_bounds__(256) void k_attn_logits(
    const int* __restrict__ ids, const float* __restrict__ emb,
    const float* __restrict__ hidden, const float* __restrict__ attn_w,
    const float* __restrict__ attn_b, float* __restrict__ logits) {
  const int wave = threadIdx.x >> 6, lane = threadIdx.x & 63;
  const int m = blockIdx.x * 4 + wave;                 // < ML
  const float4* e4 = (const float4*)(emb + (size_t)ids[0] * H);
  const float4* h4 = (const float4*)hidden;
  const float4* w4 = (const float4*)(attn_w + (size_t)m * 2 * H);
  float acc = 0.f;
#pragma unroll
  for (int c = 0; c < 8; ++c) {
    int f = lane + 64 * c;                             // 0..511 float4s
    float4 w = w4[f];
    float4 v = (f < H4) ? e4[f] : h4[f - H4];
    acc += w.x * v.x + w.y * v.y + w.z * v.z + w.w * v.w;
  }
  for (int s = 32; s; s >>= 1) acc += __shfl_down(acc, s, 64);
  if (lane == 0) logits[m] = acc + attn_b[m];
}

// ---------------- K2: softmax over ML, write weights to ws and to out
__global__ __launch_bounds__(1024) void k_softmax_attn(
    const float* __restrict__ logits, float* __restrict__ weights,
    float* __restrict__ out_attn) {
  __shared__ float red[16];
  const int t = threadIdx.x, lane = t & 63, wave = t >> 6;
  float4 x = ((const float4*)logits)[t];
  float mx = fmaxf(fmaxf(x.x, x.y), fmaxf(x.z, x.w));
  for (int s = 32; s; s >>= 1) mx = fmaxf(mx, __shfl_xor(mx, s, 64));
  if (lane == 0) red[wave] = mx;
  __syncthreads();
  float M = red[0];
#pragma unroll
  for (int i = 1; i < 16; ++i) M = fmaxf(M, red[i]);
  __syncthreads();
  float4 e;
  e.x = expf(x.x - M); e.y = expf(x.y - M);
  e.z = expf(x.z - M); e.w = expf(x.w - M);
  float s = e.x + e.y + e.z + e.w;
  for (int st = 32; st; st >>= 1) s += __shfl_xor(s, st, 64);
  if (lane == 0) red[wave] = s;
  __syncthreads();
  float S = 0.f;
#pragma unroll
  for (int i = 0; i < 16; ++i) S += red[i];
  float inv = 1.f / S;
  float4 w; w.x = e.x * inv; w.y = e.y * inv; w.z = e.z * inv; w.w = e.w * inv;
  ((float4*)weights)[t] = w;
  ((float4*)out_attn)[t] = w;
}

// ---------------- K3a: partial attn_applied, 32 blocks over m-chunks of 128
__global__ __launch_bounds__(256) void k_attn_apply_partial(
    const float* __restrict__ weights, const float* __restrict__ enc,
    float* __restrict__ partial) {
  const int t = threadIdx.x, b = blockIdx.x;
  const float4* enc4 = (const float4*)enc;
  float4 acc = {0.f, 0.f, 0.f, 0.f};
  for (int r = 0; r < 128; ++r) {
    int m = b * 128 + r;
    float w = weights[m];
    float4 v = enc4[(size_t)m * H4 + t];
    acc.x += w * v.x; acc.y += w * v.y; acc.z += w * v.z; acc.w += w * v.w;
  }
  ((float4*)partial)[b * H4 + t] = acc;
}

// ---------------- K3b: reduce 32 partials
__global__ __launch_bounds__(256) void k_attn_apply_reduce(
    const float* __restrict__ partial, float* __restrict__ applied) {
  const int t = threadIdx.x;
  const float4* p4 = (const float4*)partial;
  float4 acc = {0.f, 0.f, 0.f, 0.f};
  for (int b = 0; b < 32; ++b) {
    float4 v = p4[b * H4 + t];
    acc.x += v.x; acc.y += v.y; acc.z += v.z; acc.w += v.w;
  }
  ((float4*)applied)[t] = acc;
}

// ---------------- K4: x[i] = relu(dot(concat(e0, applied), comb_w[i]) + comb_b[i])
__global__ __launch_bounds__(256) void k_combine(
    const int* __restrict__ ids, const float* __restrict__ emb,
    const float* __restrict__ applied, const float* __restrict__ comb_w,
    const float* __restrict__ comb_b, float* __restrict__ x) {
  const int wave = threadIdx.x >> 6, lane = threadIdx.x & 63;
  const int i = blockIdx.x * 4 + wave;                 // < H
  const float4* e4 = (const float4*)(emb + (size_t)ids[0] * H);
  const float4* a4 = (const float4*)applied;
  const float4* w4 = (const float4*)(comb_w + (size_t)i * 2 * H);
  float acc = 0.f;
#pragma unroll
  for (int c = 0; c < 8; ++c) {
    int f = lane + 64 * c;
    float4 w = w4[f];
    float4 v = (f < H4) ? e4[f] : a4[f - H4];
    acc += w.x * v.x + w.y * v.y + w.z * v.z + w.w * v.w;
  }
  for (int s = 32; s; s >>= 1) acc += __shfl_down(acc, s, 64);
  if (lane == 0) x[i] = fmaxf(acc + comb_b[i], 0.f);
}

// ---------------- K5: gi[k] = dot(w_ih[k], x)+b_ih[k]; gh[k] = dot(w_hh[k], h0)+b_hh[k]
__global__ __launch_bounds__(256) void k_gates(
    const float* __restrict__ x, const float* __restrict__ hidden,
    const float* __restrict__ w_ih, const float* __restrict__ w_hh,
    const float* __restrict__ b_ih, const float* __restrict__ b_hh,
    float* __restrict__ gi, float* __restrict__ gh) {
  const int wave = threadIdx.x >> 6, lane = threadIdx.x & 63;
  const int k = blockIdx.x * 4 + wave;                 // < 3H
  const float4* x4 = (const float4*)x;
  const float4* h4 = (const float4*)hidden;
  const float4* wi4 = (const float4*)(w_ih + (size_t)k * H);
  const float4* wh4 = (const float4*)(w_hh + (size_t)k * H);
  float ai = 0.f, ah = 0.f;
#pragma unroll
  for (int c = 0; c < 4; ++c) {
    int f = lane + 64 * c;
    float4 wi = wi4[f], wh = wh4[f], vx = x4[f], vh = h4[f];
    ai += wi.x * vx.x + wi.y * vx.y + wi.z * vx.z + wi.w * vx.w;
    ah += wh.x * vh.x + wh.y * vh.y + wh.z * vh.z + wh.w * vh.w;
  }
  for (int s = 32; s; s >>= 1) {
    ai += __shfl_down(ai, s, 64);
    ah += __shfl_down(ah, s, 64);
  }
  if (lane == 0) { gi[k] = ai + b_ih[k]; gh[k] = ah + b_hh[k]; }
}

// ---------------- K6: GRU combine -> h_new (to ws and to out)
__global__ __launch_bounds__(1024) void k_gru(
    const float* __restrict__ gi, const float* __restrict__ gh,
    const float* __restrict__ hidden, float* __restrict__ hnew,
    float* __restrict__ out_h) {
  const int i = threadIdx.x;
  float r = 1.f / (1.f + expf(-(gi[i] + gh[i])));
  float z = 1.f / (1.f + expf(-(gi[H + i] + gh[H + i])));
  float n = tanhf(gi[2 * H + i] + r * gh[2 * H + i]);
  float h = (1.f - z) * n + z * hidden[i];
  hnew[i] = h;
  out_h[i] = h;
}

// ---------------- K7: logits[v] = dot(out_w[v], h_new)+out_b[v]; online (max,sumexp) partials
__global__ __launch_bounds__(256) void k_logits(
    const float* __restrict__ hnew, const float* __restrict__ out_w,
    const float* __restrict__ out_b, float* __restrict__ logits,
    float* __restrict__ pmax, float* __restrict__ psum) {
  __shared__ float sm[4], ss[4];
  const int wave = threadIdx.x >> 6, lane = threadIdx.x & 63;
  const float4* h4 = (const float4*)hnew;
  float m_w = -INFINITY, s_w = 0.f;
  const int base = blockIdx.x * 64 + wave * 16;
  for (int r = 0; r < 16; ++r) {
    const int v = base + r;
    const float4* w4 = (const float4*)(out_w + (size_t)v * H);
    float acc = 0.f;
#pragma unroll
    for (int c = 0; c < 4; ++c) {
      int f = lane + 64 * c;
      float4 w = w4[f], hv = h4[f];
      acc += w.x * hv.x + w.y * hv.y + w.z * hv.z + w.w * hv.w;
    }
    for (int s = 32; s; s >>= 1) acc += __shfl_xor(acc, s, 64);
    float logit = acc + out_b[v];
    if (lane == 0) logits[v] = logit;
    float nm = fmaxf(m_w, logit);
    s_w = s_w * expf(m_w - nm) + expf(logit - nm);
    m_w = nm;
  }
  if (lane == 0) { sm[wave] = m_w; ss[wave] = s_w; }
  __syncthreads();
  if (threadIdx.x == 0) {
    float M = fmaxf(fmaxf(sm[0], sm[1]), fmaxf(sm[2], sm[3]));
    float S = ss[0] * expf(sm[0] - M) + ss[1] * expf(sm[1] - M) +
              ss[2] * expf(sm[2] - M) + ss[3] * expf(sm[3] - M);
    pmax[blockIdx.x] = M;
    psum[blockIdx.x] = S;
  }
}

// ---------------- K8: reduce 2000 (m,s) partials -> lse
__global__ __launch_bounds__(256) void k_lse(
    const float* __restrict__ pmax, const float* __restrict__ psum,
    float* __restrict__ lse) {
  __shared__ float sm[4], ss[4];
  const int t = threadIdx.x, lane = t & 63, wave = t >> 6;
  float m = -INFINITY, s = 0.f;
  for (int i = t; i < 2000; i += 256) {
    float m2 = pmax[i], s2 = psum[i];
    float nm = fmaxf(m, m2);
    s = s * expf(m - nm) + s2 * expf(m2 - nm);
    m = nm;
  }
  for (int d = 32; d; d >>= 1) {
    float m2 = __shfl_xor(m, d, 64), s2 = __shfl_xor(s, d, 64);
    float nm = fmaxf(m, m2);
    s = s * expf(m - nm) + s2 * expf(m2 - nm);
    m = nm;
  }
  if (lane == 0) { sm[wave] = m; ss[wave] = s; }
  __syncthreads();
  if (t == 0) {
    float M = fmaxf(fmaxf(sm[0], sm[1]), fmaxf(sm[2], sm[3]));
    float S = ss[0] * expf(sm[0] - M) + ss[1] * expf(sm[1] - M) +
              ss[2] * expf(sm[2] - M) + ss[3] * expf(sm[3] - M);
    lse[0] = M + logf(S);
  }
}

// ---------------- K9: out[v] = logits[v] - lse
__global__ __launch_bounds__(256) void k_writeout(
    const float* __restrict__ logits, const float* __restrict__ lse,
    float* __restrict__ out) {
  const int v = blockIdx.x * 256 + threadIdx.x;
  out[v] = logits[v] - lse[0];
}

extern "C" void kernel_launch(void* const* d_in, const int* in_sizes, int n_in,
                              void* d_out, int out_size, void* d_ws, size_t ws_size,
                              hipStream_t stream) {
  const int*   ids    = (const int*)d_in[0];
  const float* hidden = (const float*)d_in[1];
  const float* enc    = (const float*)d_in[2];
  const float* emb    = (const float*)d_in[3];
  const float* attn_w = (const float*)d_in[4];
  const float* attn_b = (const float*)d_in[5];
  const float* comb_w = (const float*)d_in[6];
  const float* comb_b = (const float*)d_in[7];
  const float* w_ih   = (const float*)d_in[8];
  const float* w_hh   = (const float*)d_in[9];
  const float* b_ih   = (const float*)d_in[10];
  const float* b_hh   = (const float*)d_in[11];
  const float* out_w  = (const float*)d_in[12];
  const float* out_b  = (const float*)d_in[13];

  float* out        = (float*)d_out;         // [V] log_softmax
  float* out_h      = out + V;               // [H] h_new
  float* out_attn   = out + V + H;           // [ML] attn weights

  float* ws        = (float*)d_ws;
  float* ws_alog   = ws;                     // 4096
  float* ws_aw     = ws + 4096;              // 4096
  float* ws_part   = ws + 8192;              // 32*1024
  float* ws_app    = ws + 40960;             // 1024
  float* ws_x      = ws + 41984;             // 1024
  float* ws_gi     = ws + 43008;             // 3072
  float* ws_gh     = ws + 46080;             // 3072
  float* ws_hnew   = ws + 49152;             // 1024
  float* ws_logits = ws + 50176;             // 128000
  float* ws_pmax   = ws + 178176;            // 2000
  float* ws_psum   = ws + 180176;            // 2000
  float* ws_lse    = ws + 182176;            // 1

  k_attn_logits<<<ML / 4, 256, 0, stream>>>(ids, emb, hidden, attn_w, attn_b, ws_alog);
  k_softmax_attn<<<1, 1024, 0, stream>>>(ws_alog, ws_aw, out_attn);
  k_attn_apply_partial<<<32, 256, 0, stream>>>(ws_aw, enc, ws_part);
  k_attn_apply_reduce<<<1, 256, 0, stream>>>(ws_part, ws_app);
  k_combine<<<H / 4, 256, 0, stream>>>(ids, emb, ws_app, comb_w, comb_b, ws_x);
  k_gates<<<3 * H / 4, 256, 0, stream>>>(ws_x, hidden, w_ih, w_hh, b_ih, b_hh, ws_gi, ws_gh);
  k_gru<<<1, 1024, 0, stream>>>(ws_gi, ws_gh, hidden, ws_hnew, out_h);
  k_logits<<<V / 64, 256, 0, stream>>>(ws_hnew, out_w, out_b, ws_logits, ws_pmax, ws_psum);
  k_lse<<<1, 256, 0, stream>>>(ws_pmax, ws_psum, ws_lse);
  k_writeout<<<V / 256, 256, 0, stream>>>(ws_logits, ws_lse, out);
}